// Round 1
// baseline (1034.783 us; speedup 1.0000x reference)
//
#include <hip/hip_runtime.h>
#include <hip/hip_bf16.h>

#define HID 512
#define ENCD 512
#define NB 256
#define SEQ 1024
#define M_TOTAL (NB * SEQ)  // 262144

typedef short bf16x8 __attribute__((ext_vector_type(8)));
typedef float floatx4 __attribute__((ext_vector_type(4)));

__device__ __forceinline__ unsigned short f2bf(float f) {
    unsigned u = __builtin_bit_cast(unsigned, f);
    u += 0x7FFFu + ((u >> 16) & 1u);   // round-to-nearest-even
    return (unsigned short)(u >> 16);
}
__device__ __forceinline__ ushort4 cvt4(float4 a) {
    return make_ushort4(f2bf(a.x), f2bf(a.y), f2bf(a.z), f2bf(a.w));
}

// ---------------------------------------------------------------------------
// Kernel 1: B-shuffle (W_s -> fragment-major bf16) + proj_h = dh @ W_h^T
// (unchanged — verified, ~2 MB of traffic, negligible)
// ---------------------------------------------------------------------------
__global__ __launch_bounds__(256) void prep_kernel(
    const float* __restrict__ dh,      // [256][512]
    const float* __restrict__ W_h,     // [512][512]
    const float* __restrict__ W_s,     // [512][512]
    float* __restrict__ proj_h,        // [256][512]
    unsigned short* __restrict__ Bshuf)// [32768][8] bf16
{
    __shared__ float sdh[2][HID];
    const int blk = blockIdx.x;
    const int t = threadIdx.x;
    const int b0 = blk * 2;

    ((float4*)&sdh[0][0])[t] = ((const float4*)(dh + (size_t)b0 * HID))[t];

    {
        const int id   = blk * 256 + t;
        const int lane = id & 63;
        const int nj   = (id >> 6) & 7;
        const int kt   = (id >> 9) & 15;
        const int wnG  = id >> 13;
        const int n = wnG * 128 + nj * 16 + (lane & 15);
        const int k = kt * 32 + (lane >> 4) * 8;
        const float* src = W_s + (size_t)n * HID + k;
        float4 s0 = *(const float4*)src;
        float4 s1 = *(const float4*)(src + 4);
        *(ushort4*)(Bshuf + (size_t)id * 8)     = cvt4(s0);
        *(ushort4*)(Bshuf + (size_t)id * 8 + 4) = cvt4(s1);
    }
    __syncthreads();

    #pragma unroll
    for (int i = 0; i < 2; ++i) {
        const int h = t + i * 256;
        const float4* wr = (const float4*)(W_h + (size_t)h * HID);
        float acc0 = 0.f, acc1 = 0.f;
        #pragma unroll 8
        for (int e4 = 0; e4 < HID / 4; ++e4) {
            float4 w  = wr[e4];
            float4 s0 = ((const float4*)&sdh[0][0])[e4];
            float4 s1 = ((const float4*)&sdh[1][0])[e4];
            acc0 += w.x * s0.x + w.y * s0.y + w.z * s0.z + w.w * s0.w;
            acc1 += w.x * s1.x + w.y * s1.y + w.z * s1.z + w.w * s1.w;
        }
        proj_h[(size_t)b0 * HID + h]       = acc0;
        proj_h[(size_t)(b0 + 1) * HID + h] = acc1;
    }
}

// ---------------------------------------------------------------------------
// Kernel 2: fused score GEMM. Block 128M x 512N, 512 threads, wave 64x128.
// CHANGED this round:
//  - raw s_barrier + explicit lgkmcnt(0) instead of __syncthreads():
//    __syncthreads lowers to s_waitcnt vmcnt(0) which drained the A
//    prefetch every K-iter -> full loaded-HBM-latency exposure per iter.
//    Only LDS ops must be complete at the barrier; register-destined
//    global loads legally stay in flight across it.
//  - 2-iteration-deep A prefetch (static 2-reg rotation qa/qb <-> ra/rb):
//    issue-to-use distance ~= one full K-iter of MFMA work, covering HBM
//    latency. LDS remains double-buffered; write of data(kt+1) happens at
//    iter kt just before the barrier.
//  - MFMA loop nj-outer/mi-inner so first MFMAs need only bfrag[0].
// ---------------------------------------------------------------------------
__global__ __launch_bounds__(512, 2) void score_gemm(
    const float* __restrict__ enc,           // [262144][512] fp32
    const unsigned short* __restrict__ Bshuf,// fragment-major bf16
    const float* __restrict__ proj_h,        // [256][512]
    const float* __restrict__ v,             // [512]
    float* __restrict__ scores)              // [256][1024]
{
    __shared__ unsigned short sA[2][128 * 40];
    __shared__ float sred[4][128];

    const int t    = threadIdx.x;
    const int wave = t >> 6;
    const int lane = t & 63;
    const int ln15 = lane & 15;
    const int lk   = lane >> 4;
    const int m0   = blockIdx.x * 128;   // 1024 % 128 == 0 -> single batch
    const int bb   = m0 >> 10;
    const int wm   = (wave & 1) * 64;
    const int wnG  = wave >> 1;
    const int wn   = wnG * 128;

    floatx4 acc[4][8] = {};

    // A staging coords: thread owns rows r0 and r0+64, col chunk c4 (4 floats)
    const int r0 = t >> 3, c4 = t & 7;
    const float* gA0 = enc + (size_t)(m0 + r0) * ENCD + c4 * 4;
    const float* gA1 = gA0 + (size_t)64 * ENCD;
    unsigned short* wp0 = &sA[0][r0 * 40 + c4 * 4];
    unsigned short* wp1 = &sA[0][(r0 + 64) * 40 + c4 * 4];
    const int bufStride = 128 * 40;

    // B fragment base: per (kt,nj) step is 512 ushorts (1KB)
    const unsigned short* bbase = Bshuf + ((size_t)wnG * 8192 + lane) * 8;

    // ---- prologue: stage kt=0 into buf0; data(kt=1) stays in regs (qa/qb)
    float4 p0a = *(const float4*)gA0;
    float4 p0b = *(const float4*)gA1;
    float4 qa  = *(const float4*)(gA0 + 32);   // data for kt=1
    float4 qb  = *(const float4*)(gA1 + 32);
    *(ushort4*)wp0 = cvt4(p0a);
    *(ushort4*)wp1 = cvt4(p0b);
    asm volatile("s_waitcnt lgkmcnt(0)" ::: "memory");
    __builtin_amdgcn_s_barrier();
    asm volatile("" ::: "memory");

    float4 ra = {}, rb = {};

    for (int kt = 0; kt < 16; kt += 2) {
        // ================= even sub-iter: read buf0, write data(kt+1)->buf1
        if (kt + 2 < 16) {                     // issue loads for kt+2 (HBM)
            ra = *(const float4*)(gA0 + (kt + 2) * 32);
            rb = *(const float4*)(gA1 + (kt + 2) * 32);
        }
        {
            bf16x8 bfrag[8];
            #pragma unroll
            for (int nj = 0; nj < 8; ++nj)
                bfrag[nj] = *(const bf16x8*)(bbase + (size_t)(kt * 8 + nj) * 512);
            bf16x8 afrag[4];
            #pragma unroll
            for (int mi = 0; mi < 4; ++mi)
                afrag[mi] = *(const bf16x8*)(&sA[0][(wm + mi * 16 + ln15) * 40 + lk * 8]);
            #pragma unroll
            for (int nj = 0; nj < 8; ++nj)
                #pragma unroll
                for (int mi = 0; mi < 4; ++mi)
                    acc[mi][nj] = __builtin_amdgcn_mfma_f32_16x16x32_bf16(
                        afrag[mi], bfrag[nj], acc[mi][nj], 0, 0, 0);
        }
        // write data(kt+1) to buf1 (kt+1 <= 15 always in even sub-iter)
        *(ushort4*)(wp0 + bufStride) = cvt4(qa);
        *(ushort4*)(wp1 + bufStride) = cvt4(qb);
        asm volatile("s_waitcnt lgkmcnt(0)" ::: "memory");
        __builtin_amdgcn_s_barrier();
        asm volatile("" ::: "memory");

        // ================= odd sub-iter (kt+1): read buf1, write data(kt+2)->buf0
        if (kt + 3 < 16) {                     // issue loads for kt+3 (HBM)
            qa = *(const float4*)(gA0 + (kt + 3) * 32);
            qb = *(const float4*)(gA1 + (kt + 3) * 32);
        }
        {
            bf16x8 bfrag[8];
            #pragma unroll
            for (int nj = 0; nj < 8; ++nj)
                bfrag[nj] = *(const bf16x8*)(bbase + (size_t)((kt + 1) * 8 + nj) * 512);
            bf16x8 afrag[4];
            #pragma unroll
            for (int mi = 0; mi < 4; ++mi)
                afrag[mi] = *(const bf16x8*)(&sA[1][(wm + mi * 16 + ln15) * 40 + lk * 8]);
            #pragma unroll
            for (int nj = 0; nj < 8; ++nj)
                #pragma unroll
                for (int mi = 0; mi < 4; ++mi)
                    acc[mi][nj] = __builtin_amdgcn_mfma_f32_16x16x32_bf16(
                        afrag[mi], bfrag[nj], acc[mi][nj], 0, 0, 0);
        }
        if (kt + 2 < 16) {                     // write data(kt+2) to buf0
            *(ushort4*)wp0 = cvt4(ra);
            *(ushort4*)wp1 = cvt4(rb);
        }
        asm volatile("s_waitcnt lgkmcnt(0)" ::: "memory");
        __builtin_amdgcn_s_barrier();
        asm volatile("" ::: "memory");
    }

    // Epilogue: tanh + v-dot, reduce over N. C layout: col=lane&15, row=lk*4+r
    float phv[8], vv[8];
    #pragma unroll
    for (int nj = 0; nj < 8; ++nj) {
        const int n = wn + nj * 16 + ln15;
        phv[nj] = proj_h[bb * HID + n];
        vv[nj]  = v[n];
    }

    #pragma unroll
    for (int mi = 0; mi < 4; ++mi) {
        #pragma unroll
        for (int r = 0; r < 4; ++r) {
            float s = 0.f;
            #pragma unroll
            for (int nj = 0; nj < 8; ++nj) {
                float x = acc[mi][nj][r] + phv[nj];
                float e = __expf(2.f * x);
                float th = 1.f - 2.f / (e + 1.f);  // tanh, saturation-safe
                s += vv[nj] * th;
            }
            s += __shfl_xor(s, 8, 64);
            s += __shfl_xor(s, 4, 64);
            s += __shfl_xor(s, 2, 64);
            s += __shfl_xor(s, 1, 64);
            if (ln15 == 0)
                sred[wnG][wm + mi * 16 + lk * 4 + r] = s;
        }
    }
    __syncthreads();
    if (t < 128)
        scores[m0 + t] = sred[0][t] + sred[1][t] + sred[2][t] + sred[3][t];
}

// ---------------------------------------------------------------------------
// Kernel 3: softmax + context (unchanged — verified; no per-iter barriers,
// streams at whatever BW the memory system gives it)
// ---------------------------------------------------------------------------
__global__ __launch_bounds__(1024) void softmax_ctx(
    const float* __restrict__ scores,  // [256][1024]
    const float* __restrict__ enc,     // [256][1024][512]
    float* __restrict__ ctx_out,       // [256][512]
    float* __restrict__ alpha_out)     // [256][1024]
{
    __shared__ float salpha[SEQ];
    __shared__ float sctx[16][256];
    __shared__ float sbufA[16], sbufB[16];
    const int b    = blockIdx.x >> 1;
    const int half = blockIdx.x & 1;
    const int t = threadIdx.x;
    const int w = t >> 6;

    float sc = scores[(size_t)b * SEQ + t];

    float mx = sc;
    #pragma unroll
    for (int m = 32; m >= 1; m >>= 1) mx = fmaxf(mx, __shfl_xor(mx, m, 64));
    if ((t & 63) == 0) sbufA[w] = mx;
    __syncthreads();
    float gm = sbufA[0];
    #pragma unroll
    for (int i = 1; i < 16; ++i) gm = fmaxf(gm, sbufA[i]);

    float e0 = __expf(sc - gm);
    float ssum = e0;
    #pragma unroll
    for (int m = 32; m >= 1; m >>= 1) ssum += __shfl_xor(ssum, m, 64);
    if ((t & 63) == 0) sbufB[w] = ssum;
    __syncthreads();
    float tot = 0.f;
    #pragma unroll
    for (int i = 0; i < 16; ++i) tot += sbufB[i];
    const float inv = 1.f / tot;

    const float a0 = e0 * inv;
    salpha[t] = a0;
    if (half == 0) alpha_out[(size_t)b * SEQ + t] = a0;
    __syncthreads();

    // context: tx owns 4 cols at half*256 + tx*4; ty strides rows by 16
    const int tx = t & 63;
    const int ty = t >> 6;
    float4 acc = make_float4(0.f, 0.f, 0.f, 0.f);
    const float* ep = enc + (size_t)b * SEQ * ENCD + half * 256 + (size_t)tx * 4;
    #pragma unroll 8
    for (int l = ty; l < SEQ; l += 16) {
        float4 vv = *(const float4*)(ep + (size_t)l * ENCD);
        float a = salpha[l];
        acc.x += a * vv.x; acc.y += a * vv.y;
        acc.z += a * vv.z; acc.w += a * vv.w;
    }
    *(float4*)(&sctx[ty][tx * 4]) = acc;
    __syncthreads();

    if (t < 256) {
        float s = 0.f;
        #pragma unroll
        for (int y = 0; y < 16; ++y) s += sctx[y][t];
        ctx_out[(size_t)b * ENCD + half * 256 + t] = s;
    }
}

// ---------------------------------------------------------------------------
extern "C" void kernel_launch(void* const* d_in, const int* in_sizes, int n_in,
                              void* d_out, int out_size, void* d_ws, size_t ws_size,
                              hipStream_t stream) {
    const float* dh  = (const float*)d_in[0];  // decoder_hidden [256][512]
    const float* enc = (const float*)d_in[1];  // encoder_outputs [256][1024][512]
    const float* W_h = (const float*)d_in[2];  // [512][512]
    const float* W_s = (const float*)d_in[3];  // [512][512]
    const float* v   = (const float*)d_in[4];  // [1][512]

    float* ws = (float*)d_ws;
    float* proj_h = ws;                                 // 131072 floats
    float* scores = ws + 131072;                        // 262144 floats
    unsigned short* Bshuf = (unsigned short*)(ws + 131072 + 262144); // 262144 bf16

    float* ctx   = (float*)d_out;              // [256][512]
    float* alpha = (float*)d_out + NB * HID;   // [256][1024]

    prep_kernel<<<128, 256, 0, stream>>>(dh, W_h, W_s, proj_h, Bshuf);
    score_gemm<<<M_TOTAL / 128, 512, 0, stream>>>(enc, Bshuf, proj_h, v, scores);
    softmax_ctx<<<NB * 2, 1024, 0, stream>>>(scores, enc, ctx, alpha);
}